// Round 1
// baseline (312.388 us; speedup 1.0000x reference)
//
#include <hip/hip_runtime.h>

typedef unsigned short ushort_t;
typedef __bf16 bf16x8 __attribute__((ext_vector_type(8)));
typedef unsigned short ushort8_t __attribute__((ext_vector_type(8)));
typedef unsigned short ushort4_t __attribute__((ext_vector_type(4)));
typedef float floatx4 __attribute__((ext_vector_type(4)));
typedef unsigned int uint4_t __attribute__((ext_vector_type(4)));
typedef unsigned int uint2_t __attribute__((ext_vector_type(2)));

__device__ __forceinline__ ushort_t f2bf(float f) {
    unsigned int u = __float_as_uint(f);
    u += 0x7FFFu + ((u >> 16) & 1u);  // RNE
    return (ushort_t)(u >> 16);
}
__device__ __forceinline__ float bf2f(ushort_t b) {
    return __uint_as_float(((unsigned int)b) << 16);
}
__device__ __forceinline__ bf16x8 ld_frag(const ushort_t* p) {
    ushort8_t u = *(const ushort8_t*)p;
    return __builtin_bit_cast(bf16x8, u);
}
__device__ __forceinline__ unsigned pack_trunc(float lo, float hi) {
    return __builtin_amdgcn_perm(__float_as_uint(hi), __float_as_uint(lo), 0x07060302u);
}
__device__ __forceinline__ floatx4 mfma16(bf16x8 a, bf16x8 b, floatx4 c) {
    return __builtin_amdgcn_mfma_f32_16x16x32_bf16(a, b, c, 0, 0, 0);
}
// async global->LDS, 16B per lane; LDS dest = wave-uniform base + lane*16
__device__ __forceinline__ void async16(const ushort_t* g, ushort_t* l) {
    __builtin_amdgcn_global_load_lds((const __attribute__((address_space(1))) void*)g,
                                     (__attribute__((address_space(3))) void*)l, 16, 0, 0);
}

// ---------------- fp32 -> bf16 convert, two sources in one launch ----------------
__global__ __launch_bounds__(256) void cvt_dual(const float* __restrict__ s1,
                                                ushort_t* __restrict__ d1, int n1,
                                                const float* __restrict__ s2,
                                                ushort_t* __restrict__ d2, int n2) {
    int idx = blockIdx.x * 256 + threadIdx.x;
    const float* src;
    ushort_t* dst;
    if (idx < n1) {
        src = s1; dst = d1;
    } else {
        idx -= n1;
        if (idx >= n2) return;
        src = s2; dst = d2;
    }
    const float4* s = (const float4*)src + (size_t)idx * 2;
    float4 a = s[0], b = s[1];
    ushort8_t v;
    v[0] = f2bf(a.x); v[1] = f2bf(a.y); v[2] = f2bf(a.z); v[3] = f2bf(a.w);
    v[4] = f2bf(b.x); v[5] = f2bf(b.y); v[6] = f2bf(b.z); v[7] = f2bf(b.w);
    *(ushort8_t*)(dst + (size_t)idx * 8) = v;
}

// ---------------- GEMM: C[M,N] = A[M,K]*B[N,K]^T, K=1024 compile-time ----------------
// A,B bf16, both staged via global_load_lds; K-loop fully unrolled so global
// offsets fold into the instruction immediate (zero per-step VALU address math).
// MODE 0: fp32 out + bias. MODE 2: qkv split epilogue, fused RoPE, V^T store.
template <int MODE>
__global__ __launch_bounds__(256) void gemm_a(const ushort_t* __restrict__ A,
                                              const ushort_t* __restrict__ B,
                                              const float* __restrict__ bias,
                                              void* __restrict__ Cout,
                                              ushort_t* __restrict__ vt,
                                              int M, int N) {
    constexpr int K = 1024;
    __shared__ __attribute__((aligned(16))) ushort_t As[128 * 32];
    __shared__ __attribute__((aligned(16))) ushort_t Bs[128 * 32];
    const int tid = threadIdx.x;
    const int lane = tid & 63, wave = tid >> 6;
    const int quad = lane >> 4, l16 = lane & 15;
    const int wm = wave & 1, wn = wave >> 1;
    const int m0 = blockIdx.y * 128, n0 = blockIdx.x * 128;

    const ushort_t* ga = A + (size_t)(m0 + wave * 32 + (lane >> 2)) * K + (lane & 3) * 8;
    const ushort_t* gb = B + (size_t)(n0 + wave * 32 + (lane >> 2)) * K + (lane & 3) * 8;
    const ushort_t* ga2 = ga + 16 * K;
    const ushort_t* gb2 = gb + 16 * K;
    ushort_t* la = As + wave * 1024;
    ushort_t* lb = Bs + wave * 1024;

    floatx4 acc[4][4] = {};

#pragma unroll
    for (int k0 = 0; k0 < K; k0 += 32) {
        __syncthreads();
        async16(ga + k0, la);
        async16(ga2 + k0, la + 512);
        async16(gb + k0, lb);
        async16(gb2 + k0, lb + 512);
        __syncthreads();

        bf16x8 af[4], bfr[4];
#pragma unroll
        for (int mt = 0; mt < 4; ++mt)
            af[mt] = ld_frag(&As[(wm * 64 + mt * 16 + l16) * 32 + quad * 8]);
#pragma unroll
        for (int nt = 0; nt < 4; ++nt)
            bfr[nt] = ld_frag(&Bs[(wn * 64 + nt * 16 + l16) * 32 + quad * 8]);
#pragma unroll
        for (int mt = 0; mt < 4; ++mt)
#pragma unroll
            for (int nt = 0; nt < 4; ++nt)
                acc[mt][nt] = mfma16(af[mt], bfr[nt], acc[mt][nt]);
    }

    if constexpr (MODE == 2) {
        // fused RoPE on q/k heads (wave spans exactly one 64-wide head)
        if (n0 + wn * 64 < 2048) {
            float afreq = exp2f((float)l16 * (-10.0f / 15.0f));
#pragma unroll
            for (int mt = 0; mt < 4; ++mt) {
                int rowb = m0 + wm * 64 + mt * 16 + quad * 4;
#pragma unroll
                for (int r = 0; r < 4; ++r) {
                    int t = (rowb + r) & 2047;
                    float th = (float)t * afreq;
                    float sn, cs;
                    __sincosf(th, &sn, &cs);
                    float q1 = acc[mt][0][r], q2 = acc[mt][2][r];
                    acc[mt][0][r] = q1 * cs + q2 * sn;
                    acc[mt][2][r] = -q1 * sn + q2 * cs;
                }
            }
        }
    }

#pragma unroll
    for (int mt = 0; mt < 4; ++mt) {
        int row = m0 + wm * 64 + mt * 16 + quad * 4;
#pragma unroll
        for (int nt = 0; nt < 4; ++nt) {
            int nglob = n0 + wn * 64 + nt * 16 + l16;
            if constexpr (MODE == 0) {
                float bv = bias ? bias[nglob] : 0.0f;
#pragma unroll
                for (int r = 0; r < 4; ++r)
                    ((float*)Cout)[(size_t)(row + r) * N + nglob] = acc[mt][nt][r] + bv;
            } else {
                if (nglob < 2048) {
#pragma unroll
                    for (int r = 0; r < 4; ++r)
                        ((ushort_t*)Cout)[(size_t)(row + r) * 2048 + nglob] =
                            f2bf(acc[mt][nt][r]);
                } else {
                    int d = nglob & 63, hh = (nglob >> 6) & 15;
                    int bb = row >> 11, t = row & 2047;
                    ushort4_t pk;
                    pk.x = f2bf(acc[mt][nt][0]);
                    pk.y = f2bf(acc[mt][nt][1]);
                    pk.z = f2bf(acc[mt][nt][2]);
                    pk.w = f2bf(acc[mt][nt][3]);
                    *(ushort4_t*)&vt[(((size_t)bb * 16 + hh) * 64 + d) * 2048 + t] = pk;
                }
            }
        }
    }
}

// ---------------- Flash attention ----------------
// Round 6 restructure: K and V MFMA fragments are loaded DIRECTLY from global
// (L2/L3-resident; each tile consumed once, shared by the 4 waves of a block and
// the 8 blocks per (b,h)).  This removes all K/V LDS staging (was ~70% of the
// LDS-pipe traffic, the measured bottleneck) and ALL __syncthreads (only the
// per-wave Pw transpose buffer remains in LDS).  Adds T5 setprio around MFMA
// clusters and T13 defer-max (skip o/lac rescale when max growth <= 8 in log2).
#define ATT_SCALE 0.18033688011112042f /* 0.125 * log2(e) */

template <bool DIAG>
__device__ __forceinline__ void attn_step(
    const ushort_t* __restrict__ kg,  // K tile base: [128 rows t][stride 2048] cols d
    const ushort_t* __restrict__ vg,  // V^T tile base: [64 rows d][stride 2048] cols t
    ushort_t* __restrict__ Pw, const bf16x8 (&qf)[2][2],
    floatx4 (&o)[2][4], floatx4 (&lac)[2], float (&m_)[2],
    int quad, int l16, int mhi, int qrel) {
    ushort8_t ou;
#pragma unroll
    for (int j = 0; j < 8; ++j) ou[j] = 0x3F80;
    const bf16x8 vONE = __builtin_bit_cast(bf16x8, ou);

    // ---- K fragments straight from global (A-operand: rows=k, cols=d) ----
    bf16x8 kf0[8], kf1[8];
#pragma unroll
    for (int mt = 0; mt < 8; ++mt) {
        if (DIAG && mt > mhi) continue;
        const ushort_t* kr = kg + (size_t)(mt * 16 + l16) * 2048 + quad * 8;
        kf0[mt] = ld_frag(kr);
        kf1[mt] = ld_frag(kr + 32);
    }

    floatx4 s[8][2];
    __builtin_amdgcn_s_setprio(1);
#pragma unroll
    for (int mt = 0; mt < 8; ++mt) {
        if (DIAG && mt > mhi) continue;
#pragma unroll
        for (int nt = 0; nt < 2; ++nt) {
            floatx4 z = {};
            z = mfma16(kf0[mt], qf[nt][0], z);
            s[mt][nt] = mfma16(kf1[mt], qf[nt][1], z);
        }
    }
    __builtin_amdgcn_s_setprio(0);

    // ---- V fragments straight from global (B-operand: rows=d, cols=k) ----
    // Issued here so their L2 latency hides under the softmax VALU chain.
    bf16x8 vf[4][4];
#pragma unroll
    for (int kc = 0; kc < 4; ++kc) {
        if (DIAG && kc > (mhi >> 1)) continue;
#pragma unroll
        for (int ntd = 0; ntd < 4; ++ntd)
            vf[kc][ntd] =
                ld_frag(vg + (size_t)(ntd * 16 + l16) * 2048 + kc * 32 + quad * 8);
    }

    if (DIAG) {
#pragma unroll
        for (int mt = 0; mt < 8; ++mt) {
            if (mt > mhi) continue;
#pragma unroll
            for (int nt = 0; nt < 2; ++nt)
#pragma unroll
                for (int r = 0; r < 4; ++r)
                    if (mt * 16 + quad * 4 + r > qrel + nt * 16 + l16)
                        s[mt][nt][r] = -3e38f;
        }
    }

    // ---- online softmax with defer-max (T13) ----
    float mx[2];
#pragma unroll
    for (int nt = 0; nt < 2; ++nt) {
        float m0 = -3e38f;
#pragma unroll
        for (int mt = 0; mt < 8; ++mt) {
            if (DIAG && mt > mhi) continue;
            m0 = fmaxf(m0, fmaxf(fmaxf(s[mt][nt][0], s[mt][nt][1]),
                                 fmaxf(s[mt][nt][2], s[mt][nt][3])));
        }
        m0 = fmaxf(m0, __shfl_xor(m0, 16));
        m0 = fmaxf(m0, __shfl_xor(m0, 32));
        mx[nt] = m0;
    }
    bool resc =
        !__all((mx[0] - m_[0] <= 8.0f) && (mx[1] - m_[1] <= 8.0f));
    if (resc) {
        float alpha_l[2];
#pragma unroll
        for (int nt = 0; nt < 2; ++nt) {
            float mnew = fmaxf(m_[nt], mx[nt]);
            alpha_l[nt] = __builtin_amdgcn_exp2f(m_[nt] - mnew);
            m_[nt] = mnew;
        }
#pragma unroll
        for (int mtq = 0; mtq < 2; ++mtq)
#pragma unroll
            for (int r = 0; r < 4; ++r) {
                float ao = __shfl(alpha_l[mtq], quad * 4 + r);
                lac[mtq][r] *= ao;
#pragma unroll
                for (int ntd = 0; ntd < 4; ++ntd) o[mtq][ntd][r] *= ao;
            }
    }
#pragma unroll
    for (int nt = 0; nt < 2; ++nt)
#pragma unroll
        for (int mt = 0; mt < 8; ++mt) {
            if (DIAG && mt > mhi) continue;
#pragma unroll
            for (int r = 0; r < 4; ++r)
                s[mt][nt][r] = __builtin_amdgcn_exp2f(s[mt][nt][r] - m_[nt]);
        }

    // ---- P transpose through per-wave LDS (no barrier needed) ----
#pragma unroll
    for (int mt = 0; mt < 8; ++mt) {
        if (DIAG && mt > mhi) continue;
#pragma unroll
        for (int nt = 0; nt < 2; ++nt) {
            uint2_t pk;
            pk.x = pack_trunc(s[mt][nt][0], s[mt][nt][1]);
            pk.y = pack_trunc(s[mt][nt][2], s[mt][nt][3]);
            *(uint2_t*)&Pw[(nt * 16 + l16) * 136 + mt * 16 + quad * 4] = pk;
        }
    }

    __builtin_amdgcn_s_setprio(1);
#pragma unroll
    for (int kc = 0; kc < 4; ++kc) {
        if (DIAG && kc > (mhi >> 1)) continue;
        bf16x8 ap0 = ld_frag(&Pw[l16 * 136 + kc * 32 + quad * 8]);
        bf16x8 ap1 = ld_frag(&Pw[(16 + l16) * 136 + kc * 32 + quad * 8]);
        lac[0] = mfma16(ap0, vONE, lac[0]);
        lac[1] = mfma16(ap1, vONE, lac[1]);
#pragma unroll
        for (int ntd = 0; ntd < 4; ++ntd) {
            o[0][ntd] = mfma16(ap0, vf[kc][ntd], o[0][ntd]);
            o[1][ntd] = mfma16(ap1, vf[kc][ntd], o[1][ntd]);
        }
    }
    __builtin_amdgcn_s_setprio(0);
}

__global__ __launch_bounds__(256, 2) void attn_kernel(const ushort_t* __restrict__ qk,
                                                      const ushort_t* __restrict__ vt,
                                                      ushort_t* __restrict__ y) {
    // Only the per-wave P transpose buffers live in LDS now: 4 x 32x136 ushorts.
    __shared__ __attribute__((aligned(16))) ushort_t Pw_all[4 * 4352];

    const int tid = threadIdx.x, lane = tid & 63, w = tid >> 6;
    const int quad = lane >> 4, l16 = lane & 15;
    const int bh = (int)blockIdx.x >> 3, j = (int)blockIdx.x & 7;
    const int b = bh >> 4, h = bh & 15;
    ushort_t* Pw = Pw_all + w * 4352;

    const ushort_t* base_k = qk + (size_t)(b * 2048) * 2048 + 1024 + h * 64;
    const ushort_t* base_v = vt + (size_t)bh * 64 * 2048;

#pragma unroll 1
    for (int ph = 0; ph < 2; ++ph) {
        const int jj = ph ? (15 - j) : j;
        const int q0 = jj * 128 + w * 32;

        bf16x8 qf[2][2];
        {
            const ushort_t* qb = qk + (size_t)(b * 2048 + q0) * 2048 + h * 64 + quad * 8;
#pragma unroll
            for (int nt = 0; nt < 2; ++nt)
#pragma unroll
                for (int kd = 0; kd < 2; ++kd) {
                    ushort8_t raw =
                        *(const ushort8_t*)(qb + (size_t)(nt * 16 + l16) * 2048 + kd * 32);
                    uint4_t dw;
#pragma unroll
                    for (int jx = 0; jx < 4; ++jx) {
                        float f0 = bf2f(raw[2 * jx]) * ATT_SCALE;
                        float f1 = bf2f(raw[2 * jx + 1]) * ATT_SCALE;
                        dw[jx] = pack_trunc(f0, f1);
                    }
                    qf[nt][kd] = __builtin_bit_cast(bf16x8, dw);
                }
        }

        floatx4 o[2][4] = {};
        floatx4 lac[2] = {};
        float m_[2] = {-3e38f, -3e38f};

#pragma unroll 1
        for (int kt = 0; kt <= jj; ++kt) {
            const ushort_t* kg = base_k + (size_t)(kt * 128) * 2048;
            const ushort_t* vg = base_v + kt * 128;
            if (kt < jj)
                attn_step<false>(kg, vg, Pw, qf, o, lac, m_, quad, l16, 7, 0);
            else
                attn_step<true>(kg, vg, Pw, qf, o, lac, m_, quad, l16, 2 * w + 1,
                                w * 32);
        }

        ushort_t* yb = y + (size_t)(b * 2048 + q0) * 1024 + h * 64;
#pragma unroll
        for (int mtq = 0; mtq < 2; ++mtq)
#pragma unroll
            for (int r = 0; r < 4; ++r) {
                float inv = 1.0f / lac[mtq][r];
                int row = mtq * 16 + quad * 4 + r;
#pragma unroll
                for (int ntd = 0; ntd < 4; ++ntd)
                    yb[(size_t)row * 1024 + ntd * 16 + l16] = f2bf(o[mtq][ntd][r] * inv);
            }
    }
}

extern "C" void kernel_launch(void* const* d_in, const int* in_sizes, int n_in,
                              void* d_out, int out_size, void* d_ws, size_t ws_size,
                              hipStream_t stream) {
    const float* x = (const float*)d_in[0];
    const float* qkv_w = (const float*)d_in[1];
    const float* c_proj_w = (const float*)d_in[2];
    const float* c_proj_b = (const float*)d_in[3];
    float* out = (float*)d_out;

    const int M = 8192;  // B*T

    // Memory plan (time-multiplexed):
    //   d_out (32MB fp32): xb bf16 [8192x1024] during gemm1 (dead after);
    //                      final fp32 output written by gemm2 (full overwrite).
    //   ws[0,32M):  qk bf16 [8192 x 2048]       (gemm1 -> attn)
    //   ws[32,48M): vt bf16 [4][16][64][2048]   (gemm1 -> attn); first 2MB reused
    //               as wpb (c_proj_w bf16) after attn
    //   ws[48,64M): wb bf16 [3072x1024] (qkv_w) during gemm1 (dead after);
    //               y bf16 [8192x1024] written by attn (overwrites wb)
    ushort_t* qk = (ushort_t*)d_ws;
    ushort_t* vt = (ushort_t*)((char*)d_ws + (size_t)33554432);
    ushort_t* wpb = vt;
    ushort_t* wb = (ushort_t*)((char*)d_ws + (size_t)50331648);
    ushort_t* y = wb;
    ushort_t* xb = (ushort_t*)d_out;

    cvt_dual<<<dim3(5632), 256, 0, stream>>>(x, xb, M * 1024 / 8,
                                             qkv_w, wb, 3072 * 1024 / 8);

    gemm_a<2><<<dim3(3072 / 128, M / 128), 256, 0, stream>>>(
        xb, wb, nullptr, qk, vt, M, 3072);

    attn_kernel<<<dim3(512), 256, 0, stream>>>(qk, vt, y);

    cvt_dual<<<dim3(512), 256, 0, stream>>>(c_proj_w, wpb, 1024 * 1024 / 8,
                                            nullptr, nullptr, 0);

    gemm_a<0><<<dim3(1024 / 128, M / 128), 256, 0, stream>>>(
        y, wpb, c_proj_b, out, nullptr, M, 1024);
}